// Round 8
// baseline (412.478 us; speedup 1.0000x reference)
//
#include <hip/hip_runtime.h>
#include <cstdint>
#include <cstddef>

#define S_LEN   4096
#define D_MODEL 768
#define N_HEADS 12
#define HEAD_DIM 64
#define FF_DIM  3072
#define B_SZ    2
#define M_ROWS  (B_SZ * S_LEN)   // 8192
#define QKV_N   (3 * D_MODEL)    // 2304

typedef unsigned short u16;
typedef __attribute__((ext_vector_type(8))) __bf16 bf16x8;
typedef __attribute__((ext_vector_type(4))) float  f32x4;

__device__ __forceinline__ float bf2f(u16 u) {
    union { unsigned u32; float f; } cv; cv.u32 = ((unsigned)u) << 16; return cv.f;
}
__device__ __forceinline__ u16 f2bf(float f) {
    union { float f; unsigned u32; } cv; cv.f = f;
    unsigned x = cv.u32;
    unsigned r = (x + 0x7fffu + ((x >> 16) & 1u)) >> 16;
    return (u16)r;
}
// fast tanh-GELU: x * sigmoid(2*(0.79788456*(x + 0.044715 x^3)))
__device__ __forceinline__ float gelu_fast(float x) {
    float u = 0.7978845608f * (x + 0.044715f * x * x * x);
    return x / (1.f + __expf(-2.f * u));
}
// async global->LDS, 16B per lane. LDS dest must be wave-uniform base + lane*16.
__device__ __forceinline__ void async16(const void* g, void* l) {
    __builtin_amdgcn_global_load_lds(
        (const __attribute__((address_space(1))) unsigned int*)g,
        (__attribute__((address_space(3))) unsigned int*)l, 16, 0, 0);
}

// ---------------------------------------------------------------------------
// x: fp32 -> bf16 (8 elems/thread).
// ---------------------------------------------------------------------------
__global__ __launch_bounds__(256) void cvt_x(const float* __restrict__ in,
                                             u16* __restrict__ out, long n8)
{
    long i = (long)blockIdx.x * 256 + threadIdx.x;
    const long stride = (long)gridDim.x * 256;
    for (; i < n8; i += stride) {
        const float* p = in + i * 8;
        float4 a = *(const float4*)p;
        float4 b = *(const float4*)(p + 4);
        union { uint4 q; u16 el[8]; } o;
        o.el[0] = f2bf(a.x); o.el[1] = f2bf(a.y);
        o.el[2] = f2bf(a.z); o.el[3] = f2bf(a.w);
        o.el[4] = f2bf(b.x); o.el[5] = f2bf(b.y);
        o.el[6] = f2bf(b.z); o.el[7] = f2bf(b.w);
        ((uint4*)out)[i] = o.q;
    }
}

// ---------------------------------------------------------------------------
// Tiled transpose, fp32 in [R,C] -> bf16 out [C,R]. R, C multiples of 64.
// nsrc selects among up to 3 sources (blockIdx.z), each writing to
// out + z*R*C (used to fuse Wq/Wk/Wv into one dispatch).
// ---------------------------------------------------------------------------
__global__ __launch_bounds__(256) void transpose_w(const float* __restrict__ inA,
                                                   const float* __restrict__ inB,
                                                   const float* __restrict__ inC,
                                                   u16* __restrict__ out,
                                                   int R, int C)
{
    __shared__ __align__(16) u16 T[64 * 72];
    const int z = blockIdx.z;
    const float* in = (z == 0) ? inA : (z == 1) ? inB : inC;
    u16* o_ = out + (size_t)z * R * C;
    const int r0 = blockIdx.y * 64, c0 = blockIdx.x * 64;
    const int t = threadIdx.x;
    for (int v = t; v < 512; v += 256) {
        int rr = v >> 3, c8 = (v & 7) * 8;
        const float* p = in + (size_t)(r0 + rr) * C + c0 + c8;
        float4 a = *(const float4*)p;
        float4 b = *(const float4*)(p + 4);
        union { uint4 q; u16 el[8]; } o;
        o.el[0] = f2bf(a.x); o.el[1] = f2bf(a.y);
        o.el[2] = f2bf(a.z); o.el[3] = f2bf(a.w);
        o.el[4] = f2bf(b.x); o.el[5] = f2bf(b.y);
        o.el[6] = f2bf(b.z); o.el[7] = f2bf(b.w);
        *(uint4*)&T[rr * 72 + c8] = o.q;
    }
    __syncthreads();
    for (int v = t; v < 512; v += 256) {
        int cc = v >> 3, r8 = (v & 7) * 8;
        union { uint4 q; u16 el[8]; } tmp;
        #pragma unroll
        for (int e = 0; e < 8; ++e) tmp.el[e] = T[(r8 + e) * 72 + cc];
        *(uint4*)&o_[(size_t)(c0 + cc) * R + r0 + r8] = tmp.q;
    }
}

// ---------------------------------------------------------------------------
// Concatenate qkv biases (fp32 -> fp32).
// ---------------------------------------------------------------------------
__global__ __launch_bounds__(256) void pack_qkv_bias(const float* bq, const float* bk,
                                                     const float* bv, float* biasqkv)
{
    int i = blockIdx.x * 256 + threadIdx.x;
    if (i < 768) {
        biasqkv[i]        = bq[i];
        biasqkv[768 + i]  = bk[i];
        biasqkv[1536 + i] = bv[i];
    }
}

// ---------------------------------------------------------------------------
// MFMA GEMM: C[M,N] = A[M,K] @ BT[N,K]^T + bias, optional GELU.
// bf16 in, fp32 acc, output bf16 (ofp32=0) or fp32 (ofp32=1).
// 128x128 tile, BK=64 (32 MFMAs between barriers), 4 waves x 64x64 quadrant.
// Staging via global_load_lds width=16. K multiple of 64.
// ---------------------------------------------------------------------------
__global__ __launch_bounds__(256) void gemm_bt(const u16* __restrict__ A,
                                               const u16* __restrict__ BT,
                                               const float* __restrict__ bias,
                                               void* __restrict__ C,
                                               int M, int N, int K, int act, int ofp32)
{
    __shared__ __align__(16) u16 As[128 * 64];   // 16 KB
    __shared__ __align__(16) u16 Bs[128 * 64];   // 16 KB
    const int t = threadIdx.x;
    const long m0 = (long)blockIdx.y * 128;
    const long n0 = (long)blockIdx.x * 128;
    const int lane = t & 63, w = t >> 6;
    const int wm = (w >> 1) * 64, wn = (w & 1) * 64;
    const int lr = lane & 15, lq = lane >> 4;

    // staging geometry: thread t covers rows r0 + p*32, fixed col chunk
    const int r0 = t >> 3;              // 0..31
    const int col = (t & 7) * 8;        // 0..56
    const u16* pa = &A[(m0 + r0) * (long)K + col];
    const u16* pb = &BT[(n0 + r0) * (long)K + col];
    char* la = (char*)As + t * 16;      // + p*4096
    char* lb = (char*)Bs + t * 16;

    f32x4 acc[4][4] = {};

    for (int k0 = 0; k0 < K; k0 += 64) {
        #pragma unroll
        for (int p = 0; p < 4; ++p) {
            async16(pa + k0 + p * 32 * (long)K, la + p * 4096);
            async16(pb + k0 + p * 32 * (long)K, lb + p * 4096);
        }
        __syncthreads();
        #pragma unroll
        for (int ks = 0; ks < 2; ++ks) {
            bf16x8 af[4], bfr[4];
            #pragma unroll
            for (int mi = 0; mi < 4; ++mi)
                af[mi] = *(const bf16x8*)&As[(wm + mi * 16 + lr) * 64 + ks * 32 + lq * 8];
            #pragma unroll
            for (int ni = 0; ni < 4; ++ni)
                bfr[ni] = *(const bf16x8*)&Bs[(wn + ni * 16 + lr) * 64 + ks * 32 + lq * 8];
            #pragma unroll
            for (int mi = 0; mi < 4; ++mi)
                #pragma unroll
                for (int ni = 0; ni < 4; ++ni)
                    acc[mi][ni] = __builtin_amdgcn_mfma_f32_16x16x32_bf16(
                        af[mi], bfr[ni], acc[mi][ni], 0, 0, 0);
        }
        __syncthreads();
    }

    #pragma unroll
    for (int mi = 0; mi < 4; ++mi) {
        #pragma unroll
        for (int ni = 0; ni < 4; ++ni) {
            const long colg = n0 + wn + ni * 16 + lr;
            const float bv = bias[colg];
            #pragma unroll
            for (int r = 0; r < 4; ++r) {
                const long row = m0 + wm + mi * 16 + lq * 4 + r;
                float v = acc[mi][ni][r] + bv;
                if (act == 1) v = gelu_fast(v);
                if (ofp32) ((float*)C)[row * (long)N + colg] = v;
                else       ((u16*)C)[row * (long)N + colg] = f2bf(v);
            }
        }
    }
}

// ---------------------------------------------------------------------------
// MFMA sliding-window attention. One block per (chunk c, head h, batch b).
// 4 waves x 16 Q-rows; S=QK^T direct-from-global fragments; in-register
// masked softmax; P via LDS (C->A layout); O=P@V with V^T in LDS.
// ---------------------------------------------------------------------------
__global__ __launch_bounds__(256) void attn_mfma(const u16* __restrict__ qkv,
                                                 u16* __restrict__ attn_out)
{
    const int c = blockIdx.x;   // 0..63
    const int h = blockIdx.y;   // 0..11
    const int b = blockIdx.z;   // 0..1
    const int t = threadIdx.x;
    const int wave = t >> 6, lane = t & 63;
    const int lr = lane & 15, lq = lane >> 4;

    __shared__ __align__(16) u16 Ps[64 * 200];
    __shared__ __align__(16) u16 VT[64 * 200];
    __shared__ float linv[64];

    const long base = (long)b * S_LEN;
    const long qrow0 = base + c * 64;

    // stage V^T (clamped rows)
    for (int v = t; v < 1536; v += 256) {
        int j = v >> 3, d8 = (v & 7) * 8;
        int s = c * 64 - 64 + j;
        int scl = s < 0 ? 0 : (s > S_LEN - 1 ? S_LEN - 1 : s);
        uint4 raw = *(const uint4*)&qkv[(base + scl) * (long)QKV_N + 2 * D_MODEL + h * 64 + d8];
        union { uint4 q; u16 el[8]; } u; u.q = raw;
        #pragma unroll
        for (int e = 0; e < 8; ++e) VT[(d8 + e) * 200 + j] = u.el[e];
    }

    // Q fragments direct from global
    bf16x8 aq[2];
    #pragma unroll
    for (int ks = 0; ks < 2; ++ks)
        aq[ks] = *(const bf16x8*)&qkv[(qrow0 + wave * 16 + lr) * (long)QKV_N
                                      + h * 64 + ks * 32 + lq * 8];

    // S = Q @ K^T (12 n-tiles x 16 keys)
    f32x4 sacc[12];
    #pragma unroll
    for (int nt = 0; nt < 12; ++nt) {
        int key = nt * 16 + lr;
        int s = c * 64 - 64 + key;
        int scl = s < 0 ? 0 : (s > S_LEN - 1 ? S_LEN - 1 : s);
        const u16* kp = &qkv[(base + scl) * (long)QKV_N + D_MODEL + h * 64 + lq * 8];
        bf16x8 bk0 = *(const bf16x8*)kp;
        bf16x8 bk1 = *(const bf16x8*)(kp + 32);
        f32x4 z = {0.f, 0.f, 0.f, 0.f};
        z = __builtin_amdgcn_mfma_f32_16x16x32_bf16(aq[0], bk0, z, 0, 0, 0);
        z = __builtin_amdgcn_mfma_f32_16x16x32_bf16(aq[1], bk1, z, 0, 0, 0);
        sacc[nt] = z;
    }

    // masked softmax in registers (C-layout: row=wave*16+lq*4+r, col=nt*16+lr)
    float sc_[12][4];
    float m[4] = {-1e30f, -1e30f, -1e30f, -1e30f};
    #pragma unroll
    for (int nt = 0; nt < 12; ++nt) {
        const int j = nt * 16 + lr;
        const int gpos = c * 64 - 64 + j;
        #pragma unroll
        for (int r = 0; r < 4; ++r) {
            const int qi = wave * 16 + lq * 4 + r;
            const bool ok = (j >= qi) && (j <= qi + 128) && (gpos >= 0) && (gpos < S_LEN);
            const float v = ok ? sacc[nt][r] * 0.125f : -1e30f;
            sc_[nt][r] = v;
            m[r] = fmaxf(m[r], v);
        }
    }
    #pragma unroll
    for (int o = 1; o < 16; o <<= 1)
        #pragma unroll
        for (int r = 0; r < 4; ++r) m[r] = fmaxf(m[r], __shfl_xor(m[r], o));

    float sum[4] = {0.f, 0.f, 0.f, 0.f};
    #pragma unroll
    for (int nt = 0; nt < 12; ++nt)
        #pragma unroll
        for (int r = 0; r < 4; ++r) {
            const float e = __expf(sc_[nt][r] - m[r]);
            sc_[nt][r] = e;
            sum[r] += e;
        }
    #pragma unroll
    for (int o = 1; o < 16; o <<= 1)
        #pragma unroll
        for (int r = 0; r < 4; ++r) sum[r] += __shfl_xor(sum[r], o);

    #pragma unroll
    for (int nt = 0; nt < 12; ++nt)
        #pragma unroll
        for (int r = 0; r < 4; ++r)
            Ps[(wave * 16 + lq * 4 + r) * 200 + nt * 16 + lr] = f2bf(sc_[nt][r]);
    if (lr == 0) {
        #pragma unroll
        for (int r = 0; r < 4; ++r)
            linv[wave * 16 + lq * 4 + r] = 1.f / sum[r];
    }
    __syncthreads();

    // O = P @ V
    f32x4 oacc[4] = {};
    #pragma unroll
    for (int ks = 0; ks < 6; ++ks) {
        bf16x8 ap = *(const bf16x8*)&Ps[(wave * 16 + lr) * 200 + ks * 32 + lq * 8];
        #pragma unroll
        for (int nt = 0; nt < 4; ++nt) {
            bf16x8 bv = *(const bf16x8*)&VT[(nt * 16 + lr) * 200 + ks * 32 + lq * 8];
            oacc[nt] = __builtin_amdgcn_mfma_f32_16x16x32_bf16(ap, bv, oacc[nt], 0, 0, 0);
        }
    }

    #pragma unroll
    for (int nt = 0; nt < 4; ++nt) {
        #pragma unroll
        for (int r = 0; r < 4; ++r) {
            const int row = wave * 16 + lq * 4 + r;
            const float o = oacc[nt][r] * linv[row];
            attn_out[(qrow0 + row) * (long)D_MODEL + h * 64 + nt * 16 + lr] = f2bf(o);
        }
    }
}

// ---------------------------------------------------------------------------
// LayerNorm with fused residual: out = LN(a + b) * g + beta. One block per row.
// a: fp32 if af32 else bf16. b: bf16. out: fp32 if of32 else bf16.
// out may alias a in-place.
// ---------------------------------------------------------------------------
__global__ __launch_bounds__(256) void ln_kernel(const void* a, int af32,
                                                 const u16* b,
                                                 const float* __restrict__ g,
                                                 const float* __restrict__ beta,
                                                 void* out, int of32)
{
    const long r = blockIdx.x;
    const int t = threadIdx.x;
    float v[3];
    float s = 0.f, s2 = 0.f;
    #pragma unroll
    for (int ii = 0; ii < 3; ++ii) {
        const long j = ii * 256 + t;
        const long idx = r * D_MODEL + j;
        const float xa = af32 ? ((const float*)a)[idx] : bf2f(((const u16*)a)[idx]);
        const float x = xa + bf2f(b[idx]);
        v[ii] = x; s += x; s2 += x * x;
    }
    #pragma unroll
    for (int off = 32; off > 0; off >>= 1) {
        s  += __shfl_down(s, off);
        s2 += __shfl_down(s2, off);
    }
    __shared__ float rs_[4], rs2_[4];
    int w = t >> 6, lane = t & 63;
    if (lane == 0) { rs_[w] = s; rs2_[w] = s2; }
    __syncthreads();
    float S1 = rs_[0] + rs_[1] + rs_[2] + rs_[3];
    float S2 = rs2_[0] + rs2_[1] + rs2_[2] + rs2_[3];
    float mu   = S1 * (1.f / 768.f);
    float var  = S2 * (1.f / 768.f) - mu * mu;
    float rstd = rsqrtf(var + 1e-5f);
    #pragma unroll
    for (int ii = 0; ii < 3; ++ii) {
        const long j = ii * 256 + t;
        const float o = (v[ii] - mu) * rstd * g[j] + beta[j];
        if (of32) ((float*)out)[r * D_MODEL + j] = o;
        else      ((u16*)out)[r * D_MODEL + j] = f2bf(o);
    }
}

// ---------------------------------------------------------------------------
extern "C" void kernel_launch(void* const* d_in, const int* in_sizes, int n_in,
                              void* d_out, int out_size, void* d_ws, size_t ws_size,
                              hipStream_t stream)
{
    const float* x    = (const float*)d_in[0];
    const float* Wq   = (const float*)d_in[1];
    const float* bq   = (const float*)d_in[2];
    const float* Wk   = (const float*)d_in[3];
    const float* bk   = (const float*)d_in[4];
    const float* Wv   = (const float*)d_in[5];
    const float* bv   = (const float*)d_in[6];
    const float* ln1g = (const float*)d_in[7];
    const float* ln1b = (const float*)d_in[8];
    const float* W1   = (const float*)d_in[9];
    const float* b1   = (const float*)d_in[10];
    const float* W2   = (const float*)d_in[11];
    const float* b2   = (const float*)d_in[12];
    const float* ln2g = (const float*)d_in[13];
    const float* ln2b = (const float*)d_in[14];

    // workspace (~76 MB), liveness-aliased.
    char* ws = (char*)d_ws;
    size_t off = 0;
    u16* WqkvT  = (u16*)(ws + off);   off += (size_t)QKV_N * D_MODEL * 2;
    u16* W1T    = (u16*)(ws + off);   off += (size_t)FF_DIM * D_MODEL * 2;
    u16* W2T    = (u16*)(ws + off);   off += (size_t)D_MODEL * FF_DIM * 2;
    float* biasqkv = (float*)(ws + off); off += (size_t)QKV_N * 4;
    u16* big    = (u16*)(ws + off);   off += (size_t)M_ROWS * FF_DIM * 2;
    u16* x1     = (u16*)(ws + off);   off += (size_t)M_ROWS * D_MODEL * 2;

    u16* xbf    = big;
    u16* qkv    = big + (size_t)M_ROWS * D_MODEL;
    u16* hbuf   = big;
    u16* attnb  = (u16*)d_out;          // bf16 scratch in d_out, dead before FF2
    float* outf = (float*)d_out;

    dim3 blk(256);
    cvt_x<<<dim3(1024), blk, 0, stream>>>(x, xbf, (long)M_ROWS * D_MODEL / 8);
    transpose_w<<<dim3(12, 12, 3), blk, 0, stream>>>(Wq, Wk, Wv, WqkvT, 768, 768);
    transpose_w<<<dim3(48, 12, 1), blk, 0, stream>>>(W1, W1, W1, W1T, 768, 3072);
    transpose_w<<<dim3(12, 48, 1), blk, 0, stream>>>(W2, W2, W2, W2T, 3072, 768);
    pack_qkv_bias<<<dim3(3), blk, 0, stream>>>(bq, bk, bv, biasqkv);

    // qkv = x @ [Wq|Wk|Wv] + bias (bf16 out)
    gemm_bt<<<dim3(QKV_N / 128, M_ROWS / 128), blk, 0, stream>>>(
        xbf, WqkvT, biasqkv, qkv, M_ROWS, QKV_N, D_MODEL, 0, 0);
    // attention -> bf16 scratch in d_out
    attn_mfma<<<dim3(64, N_HEADS, B_SZ), blk, 0, stream>>>(qkv, attnb);
    // x1 = LN(attn + x)  (bf16 out)
    ln_kernel<<<dim3(M_ROWS), blk, 0, stream>>>(attnb, 0, xbf, ln1g, ln1b, x1, 0);
    // h = gelu(x1 @ W1 + b1)  (bf16 out; hbuf overlays xbf+qkv, both dead)
    gemm_bt<<<dim3(FF_DIM / 128, M_ROWS / 128), blk, 0, stream>>>(
        x1, W1T, b1, hbuf, M_ROWS, FF_DIM, D_MODEL, 1, 0);
    // ff = h @ W2 + b2 -> fp32 directly into d_out
    gemm_bt<<<dim3(D_MODEL / 128, M_ROWS / 128), blk, 0, stream>>>(
        hbuf, W2T, b2, outf, M_ROWS, D_MODEL, FF_DIM, 0, 1);
    // out = LN(ff + x1), fp32 in-place on d_out
    ln_kernel<<<dim3(M_ROWS), blk, 0, stream>>>(outf, 1, x1, ln2g, ln2b, outf, 1);
}

// Round 9
// 376.322 us; speedup vs baseline: 1.0961x; 1.0961x over previous
//
#include <hip/hip_runtime.h>
#include <cstdint>
#include <cstddef>

#define S_LEN   4096
#define D_MODEL 768
#define N_HEADS 12
#define HEAD_DIM 64
#define FF_DIM  3072
#define B_SZ    2
#define M_ROWS  (B_SZ * S_LEN)   // 8192
#define QKV_N   (3 * D_MODEL)    // 2304

typedef unsigned short u16;
typedef __attribute__((ext_vector_type(8))) __bf16 bf16x8;
typedef __attribute__((ext_vector_type(4))) float  f32x4;

__device__ __forceinline__ float bf2f(u16 u) {
    union { unsigned u32; float f; } cv; cv.u32 = ((unsigned)u) << 16; return cv.f;
}
__device__ __forceinline__ u16 f2bf(float f) {
    union { float f; unsigned u32; } cv; cv.f = f;
    unsigned x = cv.u32;
    unsigned r = (x + 0x7fffu + ((x >> 16) & 1u)) >> 16;
    return (u16)r;
}
// fast tanh-GELU: x * sigmoid(2*(0.79788456*(x + 0.044715 x^3)))
__device__ __forceinline__ float gelu_fast(float x) {
    float u = 0.7978845608f * (x + 0.044715f * x * x * x);
    return x / (1.f + __expf(-2.f * u));
}
// async global->LDS, 16B per lane. LDS dest is wave-uniform base + lane*16.
__device__ __forceinline__ void async16(const void* g, void* l) {
    __builtin_amdgcn_global_load_lds(
        (const __attribute__((address_space(1))) unsigned int*)g,
        (__attribute__((address_space(3))) unsigned int*)l, 16, 0, 0);
}

// ---------------------------------------------------------------------------
// x: fp32 -> bf16 (8 elems/thread).
// ---------------------------------------------------------------------------
__global__ __launch_bounds__(256) void cvt_x(const float* __restrict__ in,
                                             u16* __restrict__ out, long n8)
{
    long i = (long)blockIdx.x * 256 + threadIdx.x;
    const long stride = (long)gridDim.x * 256;
    for (; i < n8; i += stride) {
        const float* p = in + i * 8;
        float4 a = *(const float4*)p;
        float4 b = *(const float4*)(p + 4);
        union { uint4 q; u16 el[8]; } o;
        o.el[0] = f2bf(a.x); o.el[1] = f2bf(a.y);
        o.el[2] = f2bf(a.z); o.el[3] = f2bf(a.w);
        o.el[4] = f2bf(b.x); o.el[5] = f2bf(b.y);
        o.el[6] = f2bf(b.z); o.el[7] = f2bf(b.w);
        ((uint4*)out)[i] = o.q;
    }
}

// ---------------------------------------------------------------------------
// Tiled transpose, fp32 in [R,C] -> bf16 out [C,R]. blockIdx.z selects among
// up to 3 sources, each writing out + z*R*C (fuses Wq/Wk/Wv).
// ---------------------------------------------------------------------------
__global__ __launch_bounds__(256) void transpose_w(const float* __restrict__ inA,
                                                   const float* __restrict__ inB,
                                                   const float* __restrict__ inC,
                                                   u16* __restrict__ out,
                                                   int R, int C)
{
    __shared__ __align__(16) u16 T[64 * 72];
    const int z = blockIdx.z;
    const float* in = (z == 0) ? inA : (z == 1) ? inB : inC;
    u16* o_ = out + (size_t)z * R * C;
    const int r0 = blockIdx.y * 64, c0 = blockIdx.x * 64;
    const int t = threadIdx.x;
    for (int v = t; v < 512; v += 256) {
        int rr = v >> 3, c8 = (v & 7) * 8;
        const float* p = in + (size_t)(r0 + rr) * C + c0 + c8;
        float4 a = *(const float4*)p;
        float4 b = *(const float4*)(p + 4);
        union { uint4 q; u16 el[8]; } o;
        o.el[0] = f2bf(a.x); o.el[1] = f2bf(a.y);
        o.el[2] = f2bf(a.z); o.el[3] = f2bf(a.w);
        o.el[4] = f2bf(b.x); o.el[5] = f2bf(b.y);
        o.el[6] = f2bf(b.z); o.el[7] = f2bf(b.w);
        *(uint4*)&T[rr * 72 + c8] = o.q;
    }
    __syncthreads();
    for (int v = t; v < 512; v += 256) {
        int cc = v >> 3, r8 = (v & 7) * 8;
        union { uint4 q; u16 el[8]; } tmp;
        #pragma unroll
        for (int e = 0; e < 8; ++e) tmp.el[e] = T[(r8 + e) * 72 + cc];
        *(uint4*)&o_[(size_t)(c0 + cc) * R + r0 + r8] = tmp.q;
    }
}

// ---------------------------------------------------------------------------
// Concatenate qkv biases (fp32 -> fp32).
// ---------------------------------------------------------------------------
__global__ __launch_bounds__(256) void pack_qkv_bias(const float* bq, const float* bk,
                                                     const float* bv, float* biasqkv)
{
    int i = blockIdx.x * 256 + threadIdx.x;
    if (i < 768) {
        biasqkv[i]        = bq[i];
        biasqkv[768 + i]  = bk[i];
        biasqkv[1536 + i] = bv[i];
    }
}

// ---------------------------------------------------------------------------
// MFMA GEMM: C[M,N] = A[M,K] @ BT[N,K]^T + bias, optional GELU.
// bf16 in, fp32 acc, output bf16 (ofp32=0) or fp32 (ofp32=1).
// 128x128 tile, BK=64, 4 waves x 64x64 quadrant, global_load_lds staging.
// LDS rows are 8x 16B chunks; logical chunk c of row r lives at physical
// chunk c ^ (r&7)  (XOR swizzle -> conflict-free wave64 ds_read_b128:
// chunks spread uniformly, 8 lanes x 8 chunks = every bank serves 8 words).
// Staging permutes the GLOBAL source per lane instead of the LDS dest
// (global_load_lds dest is hardwired to lane-contiguous). K multiple of 64.
// ---------------------------------------------------------------------------
__global__ __launch_bounds__(256) void gemm_bt(const u16* __restrict__ A,
                                               const u16* __restrict__ BT,
                                               const float* __restrict__ bias,
                                               void* __restrict__ C,
                                               int M, int N, int K, int act, int ofp32)
{
    __shared__ __align__(16) u16 As[128 * 64];   // 16 KB
    __shared__ __align__(16) u16 Bs[128 * 64];   // 16 KB
    const int t = threadIdx.x;
    const long m0 = (long)blockIdx.y * 128;
    const long n0 = (long)blockIdx.x * 128;
    const int lane = t & 63, w = t >> 6;
    const int wm = (w >> 1) * 64, wn = (w & 1) * 64;
    const int lr = lane & 15, lq = lane >> 4;

    // staging: thread t fills LDS slot t*16B = (row=t>>3, phys chunk=t&7);
    // it must fetch global logical chunk (t&7)^(row&7). (row+32p)&7 == row&7.
    const int r0 = t >> 3;                         // 0..31
    const int cg = ((t & 7) ^ (r0 & 7)) * 8;       // swizzled source column
    const u16* pa = &A[(m0 + r0) * (long)K + cg];
    const u16* pb = &BT[(n0 + r0) * (long)K + cg];
    char* la = (char*)As + t * 16;                 // + p*4096
    char* lb = (char*)Bs + t * 16;

    f32x4 acc[4][4] = {};

    for (int k0 = 0; k0 < K; k0 += 64) {
        #pragma unroll
        for (int p = 0; p < 4; ++p) {
            async16(pa + k0 + p * 32 * (long)K, la + p * 4096);
            async16(pb + k0 + p * 32 * (long)K, lb + p * 4096);
        }
        __syncthreads();
        #pragma unroll
        for (int ks = 0; ks < 2; ++ks) {
            bf16x8 af[4], bfr[4];
            #pragma unroll
            for (int mi = 0; mi < 4; ++mi)
                af[mi] = *(const bf16x8*)&As[(wm + mi * 16 + lr) * 64
                                             + (((ks * 4 + lq) ^ (lr & 7)) * 8)];
            #pragma unroll
            for (int ni = 0; ni < 4; ++ni)
                bfr[ni] = *(const bf16x8*)&Bs[(wn + ni * 16 + lr) * 64
                                              + (((ks * 4 + lq) ^ (lr & 7)) * 8)];
            #pragma unroll
            for (int mi = 0; mi < 4; ++mi)
                #pragma unroll
                for (int ni = 0; ni < 4; ++ni)
                    acc[mi][ni] = __builtin_amdgcn_mfma_f32_16x16x32_bf16(
                        af[mi], bfr[ni], acc[mi][ni], 0, 0, 0);
        }
        __syncthreads();
    }

    #pragma unroll
    for (int mi = 0; mi < 4; ++mi) {
        #pragma unroll
        for (int ni = 0; ni < 4; ++ni) {
            const long colg = n0 + wn + ni * 16 + lr;
            const float bv = bias[colg];
            #pragma unroll
            for (int r = 0; r < 4; ++r) {
                const long row = m0 + wm + mi * 16 + lq * 4 + r;
                float v = acc[mi][ni][r] + bv;
                if (act == 1) v = gelu_fast(v);
                if (ofp32) ((float*)C)[row * (long)N + colg] = v;
                else       ((u16*)C)[row * (long)N + colg] = f2bf(v);
            }
        }
    }
}

// ---------------------------------------------------------------------------
// MFMA sliding-window attention. One block per (chunk c, head h, batch b).
// ---------------------------------------------------------------------------
__global__ __launch_bounds__(256) void attn_mfma(const u16* __restrict__ qkv,
                                                 u16* __restrict__ attn_out)
{
    const int c = blockIdx.x;   // 0..63
    const int h = blockIdx.y;   // 0..11
    const int b = blockIdx.z;   // 0..1
    const int t = threadIdx.x;
    const int wave = t >> 6, lane = t & 63;
    const int lr = lane & 15, lq = lane >> 4;

    __shared__ __align__(16) u16 Ps[64 * 200];
    __shared__ __align__(16) u16 VT[64 * 200];
    __shared__ float linv[64];

    const long base = (long)b * S_LEN;
    const long qrow0 = base + c * 64;

    // stage V^T (clamped rows)
    for (int v = t; v < 1536; v += 256) {
        int j = v >> 3, d8 = (v & 7) * 8;
        int s = c * 64 - 64 + j;
        int scl = s < 0 ? 0 : (s > S_LEN - 1 ? S_LEN - 1 : s);
        uint4 raw = *(const uint4*)&qkv[(base + scl) * (long)QKV_N + 2 * D_MODEL + h * 64 + d8];
        union { uint4 q; u16 el[8]; } u; u.q = raw;
        #pragma unroll
        for (int e = 0; e < 8; ++e) VT[(d8 + e) * 200 + j] = u.el[e];
    }

    // Q fragments direct from global
    bf16x8 aq[2];
    #pragma unroll
    for (int ks = 0; ks < 2; ++ks)
        aq[ks] = *(const bf16x8*)&qkv[(qrow0 + wave * 16 + lr) * (long)QKV_N
                                      + h * 64 + ks * 32 + lq * 8];

    // S = Q @ K^T (12 n-tiles x 16 keys)
    f32x4 sacc[12];
    #pragma unroll
    for (int nt = 0; nt < 12; ++nt) {
        int key = nt * 16 + lr;
        int s = c * 64 - 64 + key;
        int scl = s < 0 ? 0 : (s > S_LEN - 1 ? S_LEN - 1 : s);
        const u16* kp = &qkv[(base + scl) * (long)QKV_N + D_MODEL + h * 64 + lq * 8];
        bf16x8 bk0 = *(const bf16x8*)kp;
        bf16x8 bk1 = *(const bf16x8*)(kp + 32);
        f32x4 z = {0.f, 0.f, 0.f, 0.f};
        z = __builtin_amdgcn_mfma_f32_16x16x32_bf16(aq[0], bk0, z, 0, 0, 0);
        z = __builtin_amdgcn_mfma_f32_16x16x32_bf16(aq[1], bk1, z, 0, 0, 0);
        sacc[nt] = z;
    }

    // masked softmax in registers (C-layout: row=wave*16+lq*4+r, col=nt*16+lr)
    float sc_[12][4];
    float m[4] = {-1e30f, -1e30f, -1e30f, -1e30f};
    #pragma unroll
    for (int nt = 0; nt < 12; ++nt) {
        const int j = nt * 16 + lr;
        const int gpos = c * 64 - 64 + j;
        #pragma unroll
        for (int r = 0; r < 4; ++r) {
            const int qi = wave * 16 + lq * 4 + r;
            const bool ok = (j >= qi) && (j <= qi + 128) && (gpos >= 0) && (gpos < S_LEN);
            const float v = ok ? sacc[nt][r] * 0.125f : -1e30f;
            sc_[nt][r] = v;
            m[r] = fmaxf(m[r], v);
        }
    }
    #pragma unroll
    for (int o = 1; o < 16; o <<= 1)
        #pragma unroll
        for (int r = 0; r < 4; ++r) m[r] = fmaxf(m[r], __shfl_xor(m[r], o));

    float sum[4] = {0.f, 0.f, 0.f, 0.f};
    #pragma unroll
    for (int nt = 0; nt < 12; ++nt)
        #pragma unroll
        for (int r = 0; r < 4; ++r) {
            const float e = __expf(sc_[nt][r] - m[r]);
            sc_[nt][r] = e;
            sum[r] += e;
        }
    #pragma unroll
    for (int o = 1; o < 16; o <<= 1)
        #pragma unroll
        for (int r = 0; r < 4; ++r) sum[r] += __shfl_xor(sum[r], o);

    #pragma unroll
    for (int nt = 0; nt < 12; ++nt)
        #pragma unroll
        for (int r = 0; r < 4; ++r)
            Ps[(wave * 16 + lq * 4 + r) * 200 + nt * 16 + lr] = f2bf(sc_[nt][r]);
    if (lr == 0) {
        #pragma unroll
        for (int r = 0; r < 4; ++r)
            linv[wave * 16 + lq * 4 + r] = 1.f / sum[r];
    }
    __syncthreads();

    // O = P @ V
    f32x4 oacc[4] = {};
    #pragma unroll
    for (int ks = 0; ks < 6; ++ks) {
        bf16x8 ap = *(const bf16x8*)&Ps[(wave * 16 + lr) * 200 + ks * 32 + lq * 8];
        #pragma unroll
        for (int nt = 0; nt < 4; ++nt) {
            bf16x8 bv = *(const bf16x8*)&VT[(nt * 16 + lr) * 200 + ks * 32 + lq * 8];
            oacc[nt] = __builtin_amdgcn_mfma_f32_16x16x32_bf16(ap, bv, oacc[nt], 0, 0, 0);
        }
    }

    #pragma unroll
    for (int nt = 0; nt < 4; ++nt) {
        #pragma unroll
        for (int r = 0; r < 4; ++r) {
            const int row = wave * 16 + lq * 4 + r;
            const float o = oacc[nt][r] * linv[row];
            attn_out[(qrow0 + row) * (long)D_MODEL + h * 64 + nt * 16 + lr] = f2bf(o);
        }
    }
}

// ---------------------------------------------------------------------------
// LayerNorm with fused residual: out = LN(a + b) * g + beta. One block per row.
// a: fp32 if af32 else bf16. b: bf16. out: fp32 if of32 else bf16.
// out may alias a in-place.
// ---------------------------------------------------------------------------
__global__ __launch_bounds__(256) void ln_kernel(const void* a, int af32,
                                                 const u16* b,
                                                 const float* __restrict__ g,
                                                 const float* __restrict__ beta,
                                                 void* out, int of32)
{
    const long r = blockIdx.x;
    const int t = threadIdx.x;
    float v[3];
    float s = 0.f, s2 = 0.f;
    #pragma unroll
    for (int ii = 0; ii < 3; ++ii) {
        const long j = ii * 256 + t;
        const long idx = r * D_MODEL + j;
        const float xa = af32 ? ((const float*)a)[idx] : bf2f(((const u16*)a)[idx]);
        const float x = xa + bf2f(b[idx]);
        v[ii] = x; s += x; s2 += x * x;
    }
    #pragma unroll
    for (int off = 32; off > 0; off >>= 1) {
        s  += __shfl_down(s, off);
        s2 += __shfl_down(s2, off);
    }
    __shared__ float rs_[4], rs2_[4];
    int w = t >> 6, lane = t & 63;
    if (lane == 0) { rs_[w] = s; rs2_[w] = s2; }
    __syncthreads();
    float S1 = rs_[0] + rs_[1] + rs_[2] + rs_[3];
    float S2 = rs2_[0] + rs2_[1] + rs2_[2] + rs2_[3];
    float mu   = S1 * (1.f / 768.f);
    float var  = S2 * (1.f / 768.f) - mu * mu;
    float rstd = rsqrtf(var + 1e-5f);
    #pragma unroll
    for (int ii = 0; ii < 3; ++ii) {
        const long j = ii * 256 + t;
        const float o = (v[ii] - mu) * rstd * g[j] + beta[j];
        if (of32) ((float*)out)[r * D_MODEL + j] = o;
        else      ((u16*)out)[r * D_MODEL + j] = f2bf(o);
    }
}

// ---------------------------------------------------------------------------
extern "C" void kernel_launch(void* const* d_in, const int* in_sizes, int n_in,
                              void* d_out, int out_size, void* d_ws, size_t ws_size,
                              hipStream_t stream)
{
    const float* x    = (const float*)d_in[0];
    const float* Wq   = (const float*)d_in[1];
    const float* bq   = (const float*)d_in[2];
    const float* Wk   = (const float*)d_in[3];
    const float* bk   = (const float*)d_in[4];
    const float* Wv   = (const float*)d_in[5];
    const float* bv   = (const float*)d_in[6];
    const float* ln1g = (const float*)d_in[7];
    const float* ln1b = (const float*)d_in[8];
    const float* W1   = (const float*)d_in[9];
    const float* b1   = (const float*)d_in[10];
    const float* W2   = (const float*)d_in[11];
    const float* b2   = (const float*)d_in[12];
    const float* ln2g = (const float*)d_in[13];
    const float* ln2b = (const float*)d_in[14];

    // workspace (~76 MB), liveness-aliased.
    char* ws = (char*)d_ws;
    size_t off = 0;
    u16* WqkvT  = (u16*)(ws + off);   off += (size_t)QKV_N * D_MODEL * 2;
    u16* W1T    = (u16*)(ws + off);   off += (size_t)FF_DIM * D_MODEL * 2;
    u16* W2T    = (u16*)(ws + off);   off += (size_t)D_MODEL * FF_DIM * 2;
    float* biasqkv = (float*)(ws + off); off += (size_t)QKV_N * 4;
    u16* big    = (u16*)(ws + off);   off += (size_t)M_ROWS * FF_DIM * 2;
    u16* x1     = (u16*)(ws + off);   off += (size_t)M_ROWS * D_MODEL * 2;

    u16* xbf    = big;
    u16* qkv    = big + (size_t)M_ROWS * D_MODEL;
    u16* hbuf   = big;
    u16* attnb  = (u16*)d_out;          // bf16 scratch in d_out, dead before FF2
    float* outf = (float*)d_out;

    dim3 blk(256);
    cvt_x<<<dim3(1024), blk, 0, stream>>>(x, xbf, (long)M_ROWS * D_MODEL / 8);
    transpose_w<<<dim3(12, 12, 3), blk, 0, stream>>>(Wq, Wk, Wv, WqkvT, 768, 768);
    transpose_w<<<dim3(48, 12, 1), blk, 0, stream>>>(W1, W1, W1, W1T, 768, 3072);
    transpose_w<<<dim3(12, 48, 1), blk, 0, stream>>>(W2, W2, W2, W2T, 3072, 768);
    pack_qkv_bias<<<dim3(3), blk, 0, stream>>>(bq, bk, bv, biasqkv);

    // qkv = x @ [Wq|Wk|Wv] + bias (bf16 out)
    gemm_bt<<<dim3(QKV_N / 128, M_ROWS / 128), blk, 0, stream>>>(
        xbf, WqkvT, biasqkv, qkv, M_ROWS, QKV_N, D_MODEL, 0, 0);
    // attention -> bf16 scratch in d_out
    attn_mfma<<<dim3(64, N_HEADS, B_SZ), blk, 0, stream>>>(qkv, attnb);
    // x1 = LN(attn + x)  (bf16 out)
    ln_kernel<<<dim3(M_ROWS), blk, 0, stream>>>(attnb, 0, xbf, ln1g, ln1b, x1, 0);
    // h = gelu(x1 @ W1 + b1)  (bf16 out; hbuf overlays xbf+qkv, both dead)
    gemm_bt<<<dim3(FF_DIM / 128, M_ROWS / 128), blk, 0, stream>>>(
        x1, W1T, b1, hbuf, M_ROWS, FF_DIM, D_MODEL, 1, 0);
    // ff = h @ W2 + b2 -> fp32 directly into d_out
    gemm_bt<<<dim3(D_MODEL / 128, M_ROWS / 128), blk, 0, stream>>>(
        hbuf, W2T, b2, outf, M_ROWS, D_MODEL, FF_DIM, 0, 1);
    // out = LN(ff + x1), fp32 in-place on d_out
    ln_kernel<<<dim3(M_ROWS), blk, 0, stream>>>(outf, 1, x1, ln2g, ln2b, outf, 1);
}

// Round 10
// 335.448 us; speedup vs baseline: 1.2296x; 1.1218x over previous
//
#include <hip/hip_runtime.h>
#include <cstdint>
#include <cstddef>

#define S_LEN   4096
#define D_MODEL 768
#define N_HEADS 12
#define HEAD_DIM 64
#define FF_DIM  3072
#define B_SZ    2
#define M_ROWS  (B_SZ * S_LEN)   // 8192
#define QKV_N   (3 * D_MODEL)    // 2304

typedef unsigned short u16;
typedef __attribute__((ext_vector_type(8))) __bf16 bf16x8;
typedef __attribute__((ext_vector_type(4))) float  f32x4;

__device__ __forceinline__ float bf2f(u16 u) {
    union { unsigned u32; float f; } cv; cv.u32 = ((unsigned)u) << 16; return cv.f;
}
__device__ __forceinline__ u16 f2bf(float f) {
    union { float f; unsigned u32; } cv; cv.f = f;
    unsigned x = cv.u32;
    unsigned r = (x + 0x7fffu + ((x >> 16) & 1u)) >> 16;
    return (u16)r;
}
// fast tanh-GELU: x * sigmoid(2*(0.79788456*(x + 0.044715 x^3)))
__device__ __forceinline__ float gelu_fast(float x) {
    float u = 0.7978845608f * (x + 0.044715f * x * x * x);
    return x / (1.f + __expf(-2.f * u));
}
// async global->LDS, 16B per lane. LDS dest is wave-uniform base + lane*16.
__device__ __forceinline__ void async16(const void* g, void* l) {
    __builtin_amdgcn_global_load_lds(
        (const __attribute__((address_space(1))) unsigned int*)g,
        (__attribute__((address_space(3))) unsigned int*)l, 16, 0, 0);
}

// ---------------------------------------------------------------------------
// x: fp32 -> bf16 (8 elems/thread).
// ---------------------------------------------------------------------------
__global__ __launch_bounds__(256) void cvt_x(const float* __restrict__ in,
                                             u16* __restrict__ out, long n8)
{
    long i = (long)blockIdx.x * 256 + threadIdx.x;
    const long stride = (long)gridDim.x * 256;
    for (; i < n8; i += stride) {
        const float* p = in + i * 8;
        float4 a = *(const float4*)p;
        float4 b = *(const float4*)(p + 4);
        union { uint4 q; u16 el[8]; } o;
        o.el[0] = f2bf(a.x); o.el[1] = f2bf(a.y);
        o.el[2] = f2bf(a.z); o.el[3] = f2bf(a.w);
        o.el[4] = f2bf(b.x); o.el[5] = f2bf(b.y);
        o.el[6] = f2bf(b.z); o.el[7] = f2bf(b.w);
        ((uint4*)out)[i] = o.q;
    }
}

// ---------------------------------------------------------------------------
// Tiled transpose, fp32 in [R,C] -> bf16 out [C,R]. blockIdx.z selects among
// up to 3 sources, each writing out + z*R*C (fuses Wq/Wk/Wv).
// ---------------------------------------------------------------------------
__global__ __launch_bounds__(256) void transpose_w(const float* __restrict__ inA,
                                                   const float* __restrict__ inB,
                                                   const float* __restrict__ inC,
                                                   u16* __restrict__ out,
                                                   int R, int C)
{
    __shared__ __align__(16) u16 T[64 * 72];
    const int z = blockIdx.z;
    const float* in = (z == 0) ? inA : (z == 1) ? inB : inC;
    u16* o_ = out + (size_t)z * R * C;
    const int r0 = blockIdx.y * 64, c0 = blockIdx.x * 64;
    const int t = threadIdx.x;
    for (int v = t; v < 512; v += 256) {
        int rr = v >> 3, c8 = (v & 7) * 8;
        const float* p = in + (size_t)(r0 + rr) * C + c0 + c8;
        float4 a = *(const float4*)p;
        float4 b = *(const float4*)(p + 4);
        union { uint4 q; u16 el[8]; } o;
        o.el[0] = f2bf(a.x); o.el[1] = f2bf(a.y);
        o.el[2] = f2bf(a.z); o.el[3] = f2bf(a.w);
        o.el[4] = f2bf(b.x); o.el[5] = f2bf(b.y);
        o.el[6] = f2bf(b.z); o.el[7] = f2bf(b.w);
        *(uint4*)&T[rr * 72 + c8] = o.q;
    }
    __syncthreads();
    for (int v = t; v < 512; v += 256) {
        int cc = v >> 3, r8 = (v & 7) * 8;
        union { uint4 q; u16 el[8]; } tmp;
        #pragma unroll
        for (int e = 0; e < 8; ++e) tmp.el[e] = T[(r8 + e) * 72 + cc];
        *(uint4*)&o_[(size_t)(c0 + cc) * R + r0 + r8] = tmp.q;
    }
}

// ---------------------------------------------------------------------------
// Concatenate qkv biases (fp32 -> fp32).
// ---------------------------------------------------------------------------
__global__ __launch_bounds__(256) void pack_qkv_bias(const float* bq, const float* bk,
                                                     const float* bv, float* biasqkv)
{
    int i = blockIdx.x * 256 + threadIdx.x;
    if (i < 768) {
        biasqkv[i]        = bq[i];
        biasqkv[768 + i]  = bk[i];
        biasqkv[1536 + i] = bv[i];
    }
}

// ---------------------------------------------------------------------------
// MFMA GEMM: C[M,N] = A[M,K] @ BT[N,K]^T + bias, optional GELU.
// bf16 in, fp32 acc, output bf16 (ofp32=0) or fp32 (ofp32=1).
// Tile TM x 128 (TM = MI*32), BK=64, 4 waves in 2x2 quadrant layout.
// XOR-swizzled LDS chunks (conflict-free ds_read_b128, r9: 14.2M -> 0).
// XCD-aware block remap: all n-blocks of one m-strip land on one XCD
// (round-robin heuristic) -> A-tile fetched once per XCD, not once per
// n-block on 6 different XCDs (r9 FETCH showed 3x A over-fetch).
// Requires gridDim.y % 8 == 0. K multiple of 64.
// ---------------------------------------------------------------------------
template<int MI>
__global__ __launch_bounds__(256) void gemm_bt_t(const u16* __restrict__ A,
                                                 const u16* __restrict__ BT,
                                                 const float* __restrict__ bias,
                                                 void* __restrict__ C,
                                                 int M, int N, int K, int act, int ofp32)
{
    constexpr int TM = MI * 32;
    __shared__ __align__(16) u16 As[TM * 64];
    __shared__ __align__(16) u16 Bs[128 * 64];
    const int t = threadIdx.x;

    // XCD-aware remap (bijective): linear id -> (m_blk, n_blk)
    const int NX = gridDim.x, MY8 = gridDim.y >> 3;
    const int L = blockIdx.y * NX + blockIdx.x;
    const int xcd = L & 7, q = L >> 3;
    const long m0 = (long)(xcd * MY8 + q / NX) * TM;
    const long n0 = (long)(q % NX) * 128;

    const int lane = t & 63, w = t >> 6;
    const int wm = (w >> 1) * (MI * 16), wn = (w & 1) * 64;
    const int lr = lane & 15, lq = lane >> 4;

    // staging: thread t fills LDS slot t*16B = (row=t>>3, phys chunk=t&7);
    // fetches global logical chunk (t&7)^(row&7). (row+32p)&7 == row&7.
    const int r0 = t >> 3;                         // 0..31
    const int cg = ((t & 7) ^ (r0 & 7)) * 8;       // swizzled source column
    const u16* pa = &A[(m0 + r0) * (long)K + cg];
    const u16* pb = &BT[(n0 + r0) * (long)K + cg];
    char* la = (char*)As + t * 16;
    char* lb = (char*)Bs + t * 16;

    f32x4 acc[MI][4] = {};

    for (int k0 = 0; k0 < K; k0 += 64) {
        #pragma unroll
        for (int p = 0; p < MI; ++p)
            async16(pa + k0 + p * 32 * (long)K, la + p * 4096);
        #pragma unroll
        for (int p = 0; p < 4; ++p)
            async16(pb + k0 + p * 32 * (long)K, lb + p * 4096);
        __syncthreads();
        #pragma unroll
        for (int ks = 0; ks < 2; ++ks) {
            const int kc = ((ks * 4 + lq) ^ (lr & 7)) * 8;
            bf16x8 af[MI], bfr[4];
            #pragma unroll
            for (int mi = 0; mi < MI; ++mi)
                af[mi] = *(const bf16x8*)&As[(wm + mi * 16 + lr) * 64 + kc];
            #pragma unroll
            for (int ni = 0; ni < 4; ++ni)
                bfr[ni] = *(const bf16x8*)&Bs[(wn + ni * 16 + lr) * 64 + kc];
            #pragma unroll
            for (int mi = 0; mi < MI; ++mi)
                #pragma unroll
                for (int ni = 0; ni < 4; ++ni)
                    acc[mi][ni] = __builtin_amdgcn_mfma_f32_16x16x32_bf16(
                        af[mi], bfr[ni], acc[mi][ni], 0, 0, 0);
        }
        __syncthreads();
    }

    #pragma unroll
    for (int mi = 0; mi < MI; ++mi) {
        #pragma unroll
        for (int ni = 0; ni < 4; ++ni) {
            const long colg = n0 + wn + ni * 16 + lr;
            const float bv = bias[colg];
            #pragma unroll
            for (int r = 0; r < 4; ++r) {
                const long row = m0 + wm + mi * 16 + lq * 4 + r;
                float v = acc[mi][ni][r] + bv;
                if (act == 1) v = gelu_fast(v);
                if (ofp32) ((float*)C)[row * (long)N + colg] = v;
                else       ((u16*)C)[row * (long)N + colg] = f2bf(v);
            }
        }
    }
}

// ---------------------------------------------------------------------------
// MFMA sliding-window attention. One block per (chunk c, head h, batch b).
// ---------------------------------------------------------------------------
__global__ __launch_bounds__(256) void attn_mfma(const u16* __restrict__ qkv,
                                                 u16* __restrict__ attn_out)
{
    const int c = blockIdx.x;   // 0..63
    const int h = blockIdx.y;   // 0..11
    const int b = blockIdx.z;   // 0..1
    const int t = threadIdx.x;
    const int wave = t >> 6, lane = t & 63;
    const int lr = lane & 15, lq = lane >> 4;

    __shared__ __align__(16) u16 Ps[64 * 200];
    __shared__ __align__(16) u16 VT[64 * 200];
    __shared__ float linv[64];

    const long base = (long)b * S_LEN;
    const long qrow0 = base + c * 64;

    // stage V^T (clamped rows)
    for (int v = t; v < 1536; v += 256) {
        int j = v >> 3, d8 = (v & 7) * 8;
        int s = c * 64 - 64 + j;
        int scl = s < 0 ? 0 : (s > S_LEN - 1 ? S_LEN - 1 : s);
        uint4 raw = *(const uint4*)&qkv[(base + scl) * (long)QKV_N + 2 * D_MODEL + h * 64 + d8];
        union { uint4 q; u16 el[8]; } u; u.q = raw;
        #pragma unroll
        for (int e = 0; e < 8; ++e) VT[(d8 + e) * 200 + j] = u.el[e];
    }

    // Q fragments direct from global
    bf16x8 aq[2];
    #pragma unroll
    for (int ks = 0; ks < 2; ++ks)
        aq[ks] = *(const bf16x8*)&qkv[(qrow0 + wave * 16 + lr) * (long)QKV_N
                                      + h * 64 + ks * 32 + lq * 8];

    // S = Q @ K^T (12 n-tiles x 16 keys)
    f32x4 sacc[12];
    #pragma unroll
    for (int nt = 0; nt < 12; ++nt) {
        int key = nt * 16 + lr;
        int s = c * 64 - 64 + key;
        int scl = s < 0 ? 0 : (s > S_LEN - 1 ? S_LEN - 1 : s);
        const u16* kp = &qkv[(base + scl) * (long)QKV_N + D_MODEL + h * 64 + lq * 8];
        bf16x8 bk0 = *(const bf16x8*)kp;
        bf16x8 bk1 = *(const bf16x8*)(kp + 32);
        f32x4 z = {0.f, 0.f, 0.f, 0.f};
        z = __builtin_amdgcn_mfma_f32_16x16x32_bf16(aq[0], bk0, z, 0, 0, 0);
        z = __builtin_amdgcn_mfma_f32_16x16x32_bf16(aq[1], bk1, z, 0, 0, 0);
        sacc[nt] = z;
    }

    // masked softmax in registers (C-layout: row=wave*16+lq*4+r, col=nt*16+lr)
    float sc_[12][4];
    float m[4] = {-1e30f, -1e30f, -1e30f, -1e30f};
    #pragma unroll
    for (int nt = 0; nt < 12; ++nt) {
        const int j = nt * 16 + lr;
        const int gpos = c * 64 - 64 + j;
        #pragma unroll
        for (int r = 0; r < 4; ++r) {
            const int qi = wave * 16 + lq * 4 + r;
            const bool ok = (j >= qi) && (j <= qi + 128) && (gpos >= 0) && (gpos < S_LEN);
            const float v = ok ? sacc[nt][r] * 0.125f : -1e30f;
            sc_[nt][r] = v;
            m[r] = fmaxf(m[r], v);
        }
    }
    #pragma unroll
    for (int o = 1; o < 16; o <<= 1)
        #pragma unroll
        for (int r = 0; r < 4; ++r) m[r] = fmaxf(m[r], __shfl_xor(m[r], o));

    float sum[4] = {0.f, 0.f, 0.f, 0.f};
    #pragma unroll
    for (int nt = 0; nt < 12; ++nt)
        #pragma unroll
        for (int r = 0; r < 4; ++r) {
            const float e = __expf(sc_[nt][r] - m[r]);
            sc_[nt][r] = e;
            sum[r] += e;
        }
    #pragma unroll
    for (int o = 1; o < 16; o <<= 1)
        #pragma unroll
        for (int r = 0; r < 4; ++r) sum[r] += __shfl_xor(sum[r], o);

    #pragma unroll
    for (int nt = 0; nt < 12; ++nt)
        #pragma unroll
        for (int r = 0; r < 4; ++r)
            Ps[(wave * 16 + lq * 4 + r) * 200 + nt * 16 + lr] = f2bf(sc_[nt][r]);
    if (lr == 0) {
        #pragma unroll
        for (int r = 0; r < 4; ++r)
            linv[wave * 16 + lq * 4 + r] = 1.f / sum[r];
    }
    __syncthreads();

    // O = P @ V
    f32x4 oacc[4] = {};
    #pragma unroll
    for (int ks = 0; ks < 6; ++ks) {
        bf16x8 ap = *(const bf16x8*)&Ps[(wave * 16 + lr) * 200 + ks * 32 + lq * 8];
        #pragma unroll
        for (int nt = 0; nt < 4; ++nt) {
            bf16x8 bv = *(const bf16x8*)&VT[(nt * 16 + lr) * 200 + ks * 32 + lq * 8];
            oacc[nt] = __builtin_amdgcn_mfma_f32_16x16x32_bf16(ap, bv, oacc[nt], 0, 0, 0);
        }
    }

    #pragma unroll
    for (int nt = 0; nt < 4; ++nt) {
        #pragma unroll
        for (int r = 0; r < 4; ++r) {
            const int row = wave * 16 + lq * 4 + r;
            const float o = oacc[nt][r] * linv[row];
            attn_out[(qrow0 + row) * (long)D_MODEL + h * 64 + nt * 16 + lr] = f2bf(o);
        }
    }
}

// ---------------------------------------------------------------------------
// LayerNorm with fused residual: out = LN(a + b) * g + beta. One block per row.
// a: fp32 if af32 else bf16. b: bf16. out: fp32 if of32 else bf16.
// out may alias a in-place.
// ---------------------------------------------------------------------------
__global__ __launch_bounds__(256) void ln_kernel(const void* a, int af32,
                                                 const u16* b,
                                                 const float* __restrict__ g,
                                                 const float* __restrict__ beta,
                                                 void* out, int of32)
{
    const long r = blockIdx.x;
    const int t = threadIdx.x;
    float v[3];
    float s = 0.f, s2 = 0.f;
    #pragma unroll
    for (int ii = 0; ii < 3; ++ii) {
        const long j = ii * 256 + t;
        const long idx = r * D_MODEL + j;
        const float xa = af32 ? ((const float*)a)[idx] : bf2f(((const u16*)a)[idx]);
        const float x = xa + bf2f(b[idx]);
        v[ii] = x; s += x; s2 += x * x;
    }
    #pragma unroll
    for (int off = 32; off > 0; off >>= 1) {
        s  += __shfl_down(s, off);
        s2 += __shfl_down(s2, off);
    }
    __shared__ float rs_[4], rs2_[4];
    int w = t >> 6, lane = t & 63;
    if (lane == 0) { rs_[w] = s; rs2_[w] = s2; }
    __syncthreads();
    float S1 = rs_[0] + rs_[1] + rs_[2] + rs_[3];
    float S2 = rs2_[0] + rs2_[1] + rs2_[2] + rs2_[3];
    float mu   = S1 * (1.f / 768.f);
    float var  = S2 * (1.f / 768.f) - mu * mu;
    float rstd = rsqrtf(var + 1e-5f);
    #pragma unroll
    for (int ii = 0; ii < 3; ++ii) {
        const long j = ii * 256 + t;
        const float o = (v[ii] - mu) * rstd * g[j] + beta[j];
        if (of32) ((float*)out)[r * D_MODEL + j] = o;
        else      ((u16*)out)[r * D_MODEL + j] = f2bf(o);
    }
}

// ---------------------------------------------------------------------------
extern "C" void kernel_launch(void* const* d_in, const int* in_sizes, int n_in,
                              void* d_out, int out_size, void* d_ws, size_t ws_size,
                              hipStream_t stream)
{
    const float* x    = (const float*)d_in[0];
    const float* Wq   = (const float*)d_in[1];
    const float* bq   = (const float*)d_in[2];
    const float* Wk   = (const float*)d_in[3];
    const float* bk   = (const float*)d_in[4];
    const float* Wv   = (const float*)d_in[5];
    const float* bv   = (const float*)d_in[6];
    const float* ln1g = (const float*)d_in[7];
    const float* ln1b = (const float*)d_in[8];
    const float* W1   = (const float*)d_in[9];
    const float* b1   = (const float*)d_in[10];
    const float* W2   = (const float*)d_in[11];
    const float* b2   = (const float*)d_in[12];
    const float* ln2g = (const float*)d_in[13];
    const float* ln2b = (const float*)d_in[14];

    // workspace (~76 MB), liveness-aliased.
    char* ws = (char*)d_ws;
    size_t off = 0;
    u16* WqkvT  = (u16*)(ws + off);   off += (size_t)QKV_N * D_MODEL * 2;
    u16* W1T    = (u16*)(ws + off);   off += (size_t)FF_DIM * D_MODEL * 2;
    u16* W2T    = (u16*)(ws + off);   off += (size_t)D_MODEL * FF_DIM * 2;
    float* biasqkv = (float*)(ws + off); off += (size_t)QKV_N * 4;
    u16* big    = (u16*)(ws + off);   off += (size_t)M_ROWS * FF_DIM * 2;
    u16* x1     = (u16*)(ws + off);   off += (size_t)M_ROWS * D_MODEL * 2;

    u16* xbf    = big;
    u16* qkv    = big + (size_t)M_ROWS * D_MODEL;
    u16* hbuf   = big;
    u16* attnb  = (u16*)d_out;          // bf16 scratch in d_out, dead before FF2
    float* outf = (float*)d_out;

    dim3 blk(256);
    cvt_x<<<dim3(1024), blk, 0, stream>>>(x, xbf, (long)M_ROWS * D_MODEL / 8);
    transpose_w<<<dim3(12, 12, 3), blk, 0, stream>>>(Wq, Wk, Wv, WqkvT, 768, 768);
    transpose_w<<<dim3(48, 12, 1), blk, 0, stream>>>(W1, W1, W1, W1T, 768, 3072);
    transpose_w<<<dim3(12, 48, 1), blk, 0, stream>>>(W2, W2, W2, W2T, 3072, 768);
    pack_qkv_bias<<<dim3(3), blk, 0, stream>>>(bq, bk, bv, biasqkv);

    // qkv = x @ [Wq|Wk|Wv] + bias (bf16 out), 128x128 tile
    gemm_bt_t<4><<<dim3(QKV_N / 128, M_ROWS / 128), blk, 0, stream>>>(
        xbf, WqkvT, biasqkv, qkv, M_ROWS, QKV_N, D_MODEL, 0, 0);
    // attention -> bf16 scratch in d_out
    attn_mfma<<<dim3(64, N_HEADS, B_SZ), blk, 0, stream>>>(qkv, attnb);
    // x1 = LN(attn + x)  (bf16 out)
    ln_kernel<<<dim3(M_ROWS), blk, 0, stream>>>(attnb, 0, xbf, ln1g, ln1b, x1, 0);
    // h = gelu(x1 @ W1 + b1)  (bf16 out), 128x128 tile
    gemm_bt_t<4><<<dim3(FF_DIM / 128, M_ROWS / 128), blk, 0, stream>>>(
        x1, W1T, b1, hbuf, M_ROWS, FF_DIM, D_MODEL, 1, 0);
    // ff = h @ W2 + b2 -> fp32 d_out. 64x128 tile: grid 6x128=768 blocks
    // (r9: 6x64=384 was grid-starved at 1.5 blocks/CU, 2.5 TB/s achieved)
    gemm_bt_t<2><<<dim3(D_MODEL / 128, M_ROWS / 64), blk, 0, stream>>>(
        hbuf, W2T, b2, outf, M_ROWS, D_MODEL, FF_DIM, 0, 1);
    // out = LN(ff + x1), fp32 in-place on d_out
    ln_kernel<<<dim3(M_ROWS), blk, 0, stream>>>(outf, 1, x1, ln2g, ln2b, outf, 1);
}

// Round 11
// 333.112 us; speedup vs baseline: 1.2383x; 1.0070x over previous
//
#include <hip/hip_runtime.h>
#include <cstdint>
#include <cstddef>

#define S_LEN   4096
#define D_MODEL 768
#define N_HEADS 12
#define HEAD_DIM 64
#define FF_DIM  3072
#define B_SZ    2
#define M_ROWS  (B_SZ * S_LEN)   // 8192
#define QKV_N   (3 * D_MODEL)    // 2304

typedef unsigned short u16;
typedef __attribute__((ext_vector_type(8))) __bf16 bf16x8;
typedef __attribute__((ext_vector_type(4))) float  f32x4;

__device__ __forceinline__ float bf2f(u16 u) {
    union { unsigned u32; float f; } cv; cv.u32 = ((unsigned)u) << 16; return cv.f;
}
// HW bf16 convert (v_cvt_pk_bf16_f32 on gfx950, RTNE) - 1 inst vs 4 sw inst
__device__ __forceinline__ u16 f2bf(float f) {
    __bf16 b = (__bf16)f;
    union { __bf16 b; u16 u; } cv; cv.b = b; return cv.u;
}
// fast tanh-GELU with v_rcp instead of precise-div sequence:
// gelu(x) = x * sigmoid(2*0.79788456*(x + 0.044715 x^3)) = x/(1+exp(-2u)),
// u = x*(0.7978845608 + 0.035677408*x^2)
__device__ __forceinline__ float gelu_fast(float x) {
    float x2 = x * x;
    float u  = x * fmaf(0.035677408f, x2, 0.7978845608f);
    float e  = __expf(-2.f * u);
    return x * __builtin_amdgcn_rcpf(1.f + e);
}
// async global->LDS, 16B per lane. LDS dest is wave-uniform base + lane*16.
__device__ __forceinline__ void async16(const void* g, void* l) {
    __builtin_amdgcn_global_load_lds(
        (const __attribute__((address_space(1))) unsigned int*)g,
        (__attribute__((address_space(3))) unsigned int*)l, 16, 0, 0);
}

// ---------------------------------------------------------------------------
// x: fp32 -> bf16 (8 elems/thread).
// ---------------------------------------------------------------------------
__global__ __launch_bounds__(256) void cvt_x(const float* __restrict__ in,
                                             u16* __restrict__ out, long n8)
{
    long i = (long)blockIdx.x * 256 + threadIdx.x;
    const long stride = (long)gridDim.x * 256;
    for (; i < n8; i += stride) {
        const float* p = in + i * 8;
        float4 a = *(const float4*)p;
        float4 b = *(const float4*)(p + 4);
        union { uint4 q; u16 el[8]; } o;
        o.el[0] = f2bf(a.x); o.el[1] = f2bf(a.y);
        o.el[2] = f2bf(a.z); o.el[3] = f2bf(a.w);
        o.el[4] = f2bf(b.x); o.el[5] = f2bf(b.y);
        o.el[6] = f2bf(b.z); o.el[7] = f2bf(b.w);
        ((uint4*)out)[i] = o.q;
    }
}

// ---------------------------------------------------------------------------
// Tiled transpose, fp32 in [R,C] -> bf16 out [C,R]. blockIdx.z selects among
// up to 3 sources, each writing out + z*R*C (fuses Wq/Wk/Wv).
// ---------------------------------------------------------------------------
__global__ __launch_bounds__(256) void transpose_w(const float* __restrict__ inA,
                                                   const float* __restrict__ inB,
                                                   const float* __restrict__ inC,
                                                   u16* __restrict__ out,
                                                   int R, int C)
{
    __shared__ __align__(16) u16 T[64 * 72];
    const int z = blockIdx.z;
    const float* in = (z == 0) ? inA : (z == 1) ? inB : inC;
    u16* o_ = out + (size_t)z * R * C;
    const int r0 = blockIdx.y * 64, c0 = blockIdx.x * 64;
    const int t = threadIdx.x;
    for (int v = t; v < 512; v += 256) {
        int rr = v >> 3, c8 = (v & 7) * 8;
        const float* p = in + (size_t)(r0 + rr) * C + c0 + c8;
        float4 a = *(const float4*)p;
        float4 b = *(const float4*)(p + 4);
        union { uint4 q; u16 el[8]; } o;
        o.el[0] = f2bf(a.x); o.el[1] = f2bf(a.y);
        o.el[2] = f2bf(a.z); o.el[3] = f2bf(a.w);
        o.el[4] = f2bf(b.x); o.el[5] = f2bf(b.y);
        o.el[6] = f2bf(b.z); o.el[7] = f2bf(b.w);
        *(uint4*)&T[rr * 72 + c8] = o.q;
    }
    __syncthreads();
    for (int v = t; v < 512; v += 256) {
        int cc = v >> 3, r8 = (v & 7) * 8;
        union { uint4 q; u16 el[8]; } tmp;
        #pragma unroll
        for (int e = 0; e < 8; ++e) tmp.el[e] = T[(r8 + e) * 72 + cc];
        *(uint4*)&o_[(size_t)(c0 + cc) * R + r0 + r8] = tmp.q;
    }
}

// ---------------------------------------------------------------------------
// Concatenate qkv biases (fp32 -> fp32).
// ---------------------------------------------------------------------------
__global__ __launch_bounds__(256) void pack_qkv_bias(const float* bq, const float* bk,
                                                     const float* bv, float* biasqkv)
{
    int i = blockIdx.x * 256 + threadIdx.x;
    if (i < 768) {
        biasqkv[i]        = bq[i];
        biasqkv[768 + i]  = bk[i];
        biasqkv[1536 + i] = bv[i];
    }
}

// ---------------------------------------------------------------------------
// MFMA GEMM: C[M,N] = A[M,K] @ BT[N,K]^T + bias, optional GELU.
// bf16 in, fp32 acc, output bf16 (ofp32=0) or fp32 (ofp32=1).
// Tile TM x 128 (TM = MI*32), BK=64, 4 waves in 2x2 quadrant layout.
// XOR-swizzled LDS chunks (conflict-free ds_read_b128; r9: 14.2M -> 0).
// XCD-aware block remap (r10: FF2 FETCH 157 MB -> 54 MB).
// Requires gridDim.y % 8 == 0. K multiple of 64.
// ---------------------------------------------------------------------------
template<int MI>
__global__ __launch_bounds__(256) void gemm_bt_t(const u16* __restrict__ A,
                                                 const u16* __restrict__ BT,
                                                 const float* __restrict__ bias,
                                                 void* __restrict__ C,
                                                 int M, int N, int K, int act, int ofp32)
{
    constexpr int TM = MI * 32;
    __shared__ __align__(16) u16 As[TM * 64];
    __shared__ __align__(16) u16 Bs[128 * 64];
    const int t = threadIdx.x;

    // XCD-aware remap (bijective): linear id -> (m_blk, n_blk)
    const int NX = gridDim.x, MY8 = gridDim.y >> 3;
    const int L = blockIdx.y * NX + blockIdx.x;
    const int xcd = L & 7, q = L >> 3;
    const long m0 = (long)(xcd * MY8 + q / NX) * TM;
    const long n0 = (long)(q % NX) * 128;

    const int lane = t & 63, w = t >> 6;
    const int wm = (w >> 1) * (MI * 16), wn = (w & 1) * 64;
    const int lr = lane & 15, lq = lane >> 4;

    // staging: thread t fills LDS slot t*16B = (row=t>>3, phys chunk=t&7);
    // fetches global logical chunk (t&7)^(row&7). (row+32p)&7 == row&7.
    const int r0 = t >> 3;                         // 0..31
    const int cg = ((t & 7) ^ (r0 & 7)) * 8;       // swizzled source column
    const u16* pa = &A[(m0 + r0) * (long)K + cg];
    const u16* pb = &BT[(n0 + r0) * (long)K + cg];
    char* la = (char*)As + t * 16;
    char* lb = (char*)Bs + t * 16;

    f32x4 acc[MI][4] = {};

    for (int k0 = 0; k0 < K; k0 += 64) {
        #pragma unroll
        for (int p = 0; p < MI; ++p)
            async16(pa + k0 + p * 32 * (long)K, la + p * 4096);
        #pragma unroll
        for (int p = 0; p < 4; ++p)
            async16(pb + k0 + p * 32 * (long)K, lb + p * 4096);
        __syncthreads();
        #pragma unroll
        for (int ks = 0; ks < 2; ++ks) {
            const int kc = ((ks * 4 + lq) ^ (lr & 7)) * 8;
            bf16x8 af[MI], bfr[4];
            #pragma unroll
            for (int mi = 0; mi < MI; ++mi)
                af[mi] = *(const bf16x8*)&As[(wm + mi * 16 + lr) * 64 + kc];
            #pragma unroll
            for (int ni = 0; ni < 4; ++ni)
                bfr[ni] = *(const bf16x8*)&Bs[(wn + ni * 16 + lr) * 64 + kc];
            #pragma unroll
            for (int mi = 0; mi < MI; ++mi)
                #pragma unroll
                for (int ni = 0; ni < 4; ++ni)
                    acc[mi][ni] = __builtin_amdgcn_mfma_f32_16x16x32_bf16(
                        af[mi], bfr[ni], acc[mi][ni], 0, 0, 0);
        }
        __syncthreads();
    }

    #pragma unroll
    for (int mi = 0; mi < MI; ++mi) {
        #pragma unroll
        for (int ni = 0; ni < 4; ++ni) {
            const long colg = n0 + wn + ni * 16 + lr;
            const float bv = bias[colg];
            #pragma unroll
            for (int r = 0; r < 4; ++r) {
                const long row = m0 + wm + mi * 16 + lq * 4 + r;
                float v = acc[mi][ni][r] + bv;
                if (act == 1) v = gelu_fast(v);
                if (ofp32) ((float*)C)[row * (long)N + colg] = v;
                else       ((u16*)C)[row * (long)N + colg] = f2bf(v);
            }
        }
    }
}

// ---------------------------------------------------------------------------
// MFMA sliding-window attention. One block per (chunk c, head h, batch b).
// ---------------------------------------------------------------------------
__global__ __launch_bounds__(256) void attn_mfma(const u16* __restrict__ qkv,
                                                 u16* __restrict__ attn_out)
{
    const int c = blockIdx.x;   // 0..63
    const int h = blockIdx.y;   // 0..11
    const int b = blockIdx.z;   // 0..1
    const int t = threadIdx.x;
    const int wave = t >> 6, lane = t & 63;
    const int lr = lane & 15, lq = lane >> 4;

    __shared__ __align__(16) u16 Ps[64 * 200];
    __shared__ __align__(16) u16 VT[64 * 200];
    __shared__ float linv[64];

    const long base = (long)b * S_LEN;
    const long qrow0 = base + c * 64;

    // stage V^T (clamped rows)
    for (int v = t; v < 1536; v += 256) {
        int j = v >> 3, d8 = (v & 7) * 8;
        int s = c * 64 - 64 + j;
        int scl = s < 0 ? 0 : (s > S_LEN - 1 ? S_LEN - 1 : s);
        uint4 raw = *(const uint4*)&qkv[(base + scl) * (long)QKV_N + 2 * D_MODEL + h * 64 + d8];
        union { uint4 q; u16 el[8]; } u; u.q = raw;
        #pragma unroll
        for (int e = 0; e < 8; ++e) VT[(d8 + e) * 200 + j] = u.el[e];
    }

    // Q fragments direct from global
    bf16x8 aq[2];
    #pragma unroll
    for (int ks = 0; ks < 2; ++ks)
        aq[ks] = *(const bf16x8*)&qkv[(qrow0 + wave * 16 + lr) * (long)QKV_N
                                      + h * 64 + ks * 32 + lq * 8];

    // S = Q @ K^T (12 n-tiles x 16 keys)
    f32x4 sacc[12];
    #pragma unroll
    for (int nt = 0; nt < 12; ++nt) {
        int key = nt * 16 + lr;
        int s = c * 64 - 64 + key;
        int scl = s < 0 ? 0 : (s > S_LEN - 1 ? S_LEN - 1 : s);
        const u16* kp = &qkv[(base + scl) * (long)QKV_N + D_MODEL + h * 64 + lq * 8];
        bf16x8 bk0 = *(const bf16x8*)kp;
        bf16x8 bk1 = *(const bf16x8*)(kp + 32);
        f32x4 z = {0.f, 0.f, 0.f, 0.f};
        z = __builtin_amdgcn_mfma_f32_16x16x32_bf16(aq[0], bk0, z, 0, 0, 0);
        z = __builtin_amdgcn_mfma_f32_16x16x32_bf16(aq[1], bk1, z, 0, 0, 0);
        sacc[nt] = z;
    }

    // masked softmax in registers (C-layout: row=wave*16+lq*4+r, col=nt*16+lr)
    float sc_[12][4];
    float m[4] = {-1e30f, -1e30f, -1e30f, -1e30f};
    #pragma unroll
    for (int nt = 0; nt < 12; ++nt) {
        const int j = nt * 16 + lr;
        const int gpos = c * 64 - 64 + j;
        #pragma unroll
        for (int r = 0; r < 4; ++r) {
            const int qi = wave * 16 + lq * 4 + r;
            const bool ok = (j >= qi) && (j <= qi + 128) && (gpos >= 0) && (gpos < S_LEN);
            const float v = ok ? sacc[nt][r] * 0.125f : -1e30f;
            sc_[nt][r] = v;
            m[r] = fmaxf(m[r], v);
        }
    }
    #pragma unroll
    for (int o = 1; o < 16; o <<= 1)
        #pragma unroll
        for (int r = 0; r < 4; ++r) m[r] = fmaxf(m[r], __shfl_xor(m[r], o));

    float sum[4] = {0.f, 0.f, 0.f, 0.f};
    #pragma unroll
    for (int nt = 0; nt < 12; ++nt)
        #pragma unroll
        for (int r = 0; r < 4; ++r) {
            const float e = __expf(sc_[nt][r] - m[r]);
            sc_[nt][r] = e;
            sum[r] += e;
        }
    #pragma unroll
    for (int o = 1; o < 16; o <<= 1)
        #pragma unroll
        for (int r = 0; r < 4; ++r) sum[r] += __shfl_xor(sum[r], o);

    #pragma unroll
    for (int nt = 0; nt < 12; ++nt)
        #pragma unroll
        for (int r = 0; r < 4; ++r)
            Ps[(wave * 16 + lq * 4 + r) * 200 + nt * 16 + lr] = f2bf(sc_[nt][r]);
    if (lr == 0) {
        #pragma unroll
        for (int r = 0; r < 4; ++r)
            linv[wave * 16 + lq * 4 + r] = 1.f / sum[r];
    }
    __syncthreads();

    // O = P @ V
    f32x4 oacc[4] = {};
    #pragma unroll
    for (int ks = 0; ks < 6; ++ks) {
        bf16x8 ap = *(const bf16x8*)&Ps[(wave * 16 + lr) * 200 + ks * 32 + lq * 8];
        #pragma unroll
        for (int nt = 0; nt < 4; ++nt) {
            bf16x8 bv = *(const bf16x8*)&VT[(nt * 16 + lr) * 200 + ks * 32 + lq * 8];
            oacc[nt] = __builtin_amdgcn_mfma_f32_16x16x32_bf16(ap, bv, oacc[nt], 0, 0, 0);
        }
    }

    #pragma unroll
    for (int nt = 0; nt < 4; ++nt) {
        #pragma unroll
        for (int r = 0; r < 4; ++r) {
            const int row = wave * 16 + lq * 4 + r;
            const float o = oacc[nt][r] * linv[row];
            attn_out[(qrow0 + row) * (long)D_MODEL + h * 64 + nt * 16 + lr] = f2bf(o);
        }
    }
}

// ---------------------------------------------------------------------------
// LayerNorm with fused residual: out = LN(a + b) * g + beta. One block per row.
// a: fp32 if af32 else bf16. b: bf16. out: fp32 if of32 else bf16.
// out may alias a in-place.
// ---------------------------------------------------------------------------
__global__ __launch_bounds__(256) void ln_kernel(const void* a, int af32,
                                                 const u16* b,
                                                 const float* __restrict__ g,
                                                 const float* __restrict__ beta,
                                                 void* out, int of32)
{
    const long r = blockIdx.x;
    const int t = threadIdx.x;
    float v[3];
    float s = 0.f, s2 = 0.f;
    #pragma unroll
    for (int ii = 0; ii < 3; ++ii) {
        const long j = ii * 256 + t;
        const long idx = r * D_MODEL + j;
        const float xa = af32 ? ((const float*)a)[idx] : bf2f(((const u16*)a)[idx]);
        const float x = xa + bf2f(b[idx]);
        v[ii] = x; s += x; s2 += x * x;
    }
    #pragma unroll
    for (int off = 32; off > 0; off >>= 1) {
        s  += __shfl_down(s, off);
        s2 += __shfl_down(s2, off);
    }
    __shared__ float rs_[4], rs2_[4];
    int w = t >> 6, lane = t & 63;
    if (lane == 0) { rs_[w] = s; rs2_[w] = s2; }
    __syncthreads();
    float S1 = rs_[0] + rs_[1] + rs_[2] + rs_[3];
    float S2 = rs2_[0] + rs2_[1] + rs2_[2] + rs2_[3];
    float mu   = S1 * (1.f / 768.f);
    float var  = S2 * (1.f / 768.f) - mu * mu;
    float rstd = rsqrtf(var + 1e-5f);
    #pragma unroll
    for (int ii = 0; ii < 3; ++ii) {
        const long j = ii * 256 + t;
        const float o = (v[ii] - mu) * rstd * g[j] + beta[j];
        if (of32) ((float*)out)[r * D_MODEL + j] = o;
        else      ((u16*)out)[r * D_MODEL + j] = f2bf(o);
    }
}

// ---------------------------------------------------------------------------
extern "C" void kernel_launch(void* const* d_in, const int* in_sizes, int n_in,
                              void* d_out, int out_size, void* d_ws, size_t ws_size,
                              hipStream_t stream)
{
    const float* x    = (const float*)d_in[0];
    const float* Wq   = (const float*)d_in[1];
    const float* bq   = (const float*)d_in[2];
    const float* Wk   = (const float*)d_in[3];
    const float* bk   = (const float*)d_in[4];
    const float* Wv   = (const float*)d_in[5];
    const float* bv   = (const float*)d_in[6];
    const float* ln1g = (const float*)d_in[7];
    const float* ln1b = (const float*)d_in[8];
    const float* W1   = (const float*)d_in[9];
    const float* b1   = (const float*)d_in[10];
    const float* W2   = (const float*)d_in[11];
    const float* b2   = (const float*)d_in[12];
    const float* ln2g = (const float*)d_in[13];
    const float* ln2b = (const float*)d_in[14];

    // workspace (~76 MB), liveness-aliased.
    char* ws = (char*)d_ws;
    size_t off = 0;
    u16* WqkvT  = (u16*)(ws + off);   off += (size_t)QKV_N * D_MODEL * 2;
    u16* W1T    = (u16*)(ws + off);   off += (size_t)FF_DIM * D_MODEL * 2;
    u16* W2T    = (u16*)(ws + off);   off += (size_t)D_MODEL * FF_DIM * 2;
    float* biasqkv = (float*)(ws + off); off += (size_t)QKV_N * 4;
    u16* big    = (u16*)(ws + off);   off += (size_t)M_ROWS * FF_DIM * 2;
    u16* x1     = (u16*)(ws + off);   off += (size_t)M_ROWS * D_MODEL * 2;

    u16* xbf    = big;
    u16* qkv    = big + (size_t)M_ROWS * D_MODEL;
    u16* hbuf   = big;
    u16* attnb  = (u16*)d_out;          // bf16 scratch in d_out, dead before FF2
    float* outf = (float*)d_out;

    dim3 blk(256);
    cvt_x<<<dim3(1024), blk, 0, stream>>>(x, xbf, (long)M_ROWS * D_MODEL / 8);
    transpose_w<<<dim3(12, 12, 3), blk, 0, stream>>>(Wq, Wk, Wv, WqkvT, 768, 768);
    transpose_w<<<dim3(48, 12, 1), blk, 0, stream>>>(W1, W1, W1, W1T, 768, 3072);
    transpose_w<<<dim3(12, 48, 1), blk, 0, stream>>>(W2, W2, W2, W2T, 3072, 768);
    pack_qkv_bias<<<dim3(3), blk, 0, stream>>>(bq, bk, bv, biasqkv);

    // qkv = x @ [Wq|Wk|Wv] + bias (bf16 out), 128x128 tile
    gemm_bt_t<4><<<dim3(QKV_N / 128, M_ROWS / 128), blk, 0, stream>>>(
        xbf, WqkvT, biasqkv, qkv, M_ROWS, QKV_N, D_MODEL, 0, 0);
    // attention -> bf16 scratch in d_out
    attn_mfma<<<dim3(64, N_HEADS, B_SZ), blk, 0, stream>>>(qkv, attnb);
    // x1 = LN(attn + x)  (bf16 out)
    ln_kernel<<<dim3(M_ROWS), blk, 0, stream>>>(attnb, 0, xbf, ln1g, ln1b, x1, 0);
    // h = gelu(x1 @ W1 + b1)  (bf16 out), 128x128 tile
    gemm_bt_t<4><<<dim3(FF_DIM / 128, M_ROWS / 128), blk, 0, stream>>>(
        x1, W1T, b1, hbuf, M_ROWS, FF_DIM, D_MODEL, 1, 0);
    // ff = h @ W2 + b2 -> fp32 d_out, 64x128 tile (grid 6x128, 3 blocks/CU)
    gemm_bt_t<2><<<dim3(D_MODEL / 128, M_ROWS / 64), blk, 0, stream>>>(
        hbuf, W2T, b2, outf, M_ROWS, D_MODEL, FF_DIM, 0, 1);
    // out = LN(ff + x1), fp32 in-place on d_out
    ln_kernel<<<dim3(M_ROWS), blk, 0, stream>>>(outf, 1, x1, ln2g, ln2b, outf, 1);
}